// Round 1
// baseline (2765.354 us; speedup 1.0000x reference)
//
#include <hip/hip_runtime.h>

#define NN 10000
#define EE 100000
#define CC 64
#define LL 9
#define RR 9
#define HH 8
#define NLC (NN*LL*CC)

__device__ __forceinline__ float sigmoidf_(float x){ return 1.0f/(1.0f+__expf(-x)); }

// K1: xsrc = x@W_src (+b_src on l==0), xdst = x@W_dst   (4 rows per 256-thread block)
__global__ __launch_bounds__(256) void k_node_lin(
    const float* __restrict__ x, const float* __restrict__ Ws, const float* __restrict__ bs,
    const float* __restrict__ Wd, float* __restrict__ xs, float* __restrict__ xd)
{
  const int wid = threadIdx.x >> 6;
  const int c   = threadIdx.x & 63;
  const int row = blockIdx.x*4 + wid;   // < NN*LL (exact multiple of 4)
  __shared__ float xr[4][64];
  xr[wid][c] = x[row*64 + c];
  __syncthreads();
  float as = 0.f, ad = 0.f;
  #pragma unroll 8
  for (int k=0;k<64;k++){ float xv = xr[wid][k]; as += xv*Ws[k*64+c]; ad += xv*Wd[k*64+c]; }
  if (row % LL == 0) as += bs[c];
  xs[row*64+c] = as;
  xd[row*64+c] = ad;
}

// K2: per-edge radial MLP + gather + cp_tp1 (l=0 row) + alpha -> logits + segment max
__global__ __launch_bounds__(256) void k_edge_a(
    const float* __restrict__ xsrc, const float* __restrict__ xdst,
    const float* __restrict__ eattr, const float* __restrict__ escal,
    const float* __restrict__ w1, const float* __restrict__ b1,
    const float* __restrict__ lnw, const float* __restrict__ lnb,
    const float* __restrict__ w2, const float* __restrict__ woff,
    const float* __restrict__ U1, const float* __restrict__ V1, const float* __restrict__ Y1,
    const float* __restrict__ Wa, const float* __restrict__ ba,
    const float* __restrict__ adot,
    const int* __restrict__ esrc, const int* __restrict__ edst,
    float* __restrict__ alog, unsigned int* __restrict__ amaxu)
{
  const int wid = threadIdx.x >> 6;
  const int c   = threadIdx.x & 63;
  const int e   = blockIdx.x*4 + wid;   // EE multiple of 4
  __shared__ float sbuf[4][64];
  __shared__ float sh9[4][9];
  __shared__ float sU1[81], sV1[81], sY1[81];
  __shared__ float m0[4][64];
  const int src = esrc[e], dst = edst[e];
  sbuf[wid][c] = escal[e*64+c];
  if (c<9) sh9[wid][c] = eattr[e*9+c];
  for (int i=threadIdx.x; i<81; i+=256){ sU1[i]=U1[i]; sV1[i]=V1[i]; sY1[i]=Y1[i]; }
  __syncthreads();
  // radial layer 1 + LN + silu
  float hh = b1[c];
  #pragma unroll 8
  for (int k=0;k<64;k++) hh += sbuf[wid][k]*w1[k*64+c];
  float s = hh;
  #pragma unroll
  for (int m=1;m<64;m<<=1) s += __shfl_xor(s,m,64);
  const float mean = s*(1.0f/64.0f);
  const float dv = hh-mean;
  float q = dv*dv;
  #pragma unroll
  for (int m=1;m<64;m<<=1) q += __shfl_xor(q,m,64);
  const float inv = rsqrtf(q*(1.0f/64.0f)+1e-5f);
  const float g = dv*inv*lnw[c]+lnb[c];
  const float h2 = g*sigmoidf_(g);
  __syncthreads();
  sbuf[wid][c] = h2;
  __syncthreads();
  // gather msg rows
  float msg[9];
  { const float* ps = xsrc + (size_t)src*576 + c;
    const float* pd = xdst + (size_t)dst*576 + c;
    #pragma unroll
    for (int l=0;l<9;l++) msg[l] = ps[l*64] + pd[l*64]; }
  // cp_tp1, only l=0 output needed here
  float m0v = 0.f;
  #pragma unroll
  for (int r=0;r<9;r++){
    float wvv = woff[r*64+c];
    #pragma unroll 8
    for (int k=0;k<64;k++) wvv += sbuf[wid][k]*w2[k*576+r*64+c];
    float yv=0.f, xvv=0.f;
    #pragma unroll
    for (int l=0;l<9;l++){ yv += sh9[wid][l]*sY1[l*9+r]; xvv += msg[l]*sV1[l*9+r]; }
    m0v += xvv*yv*wvv*sU1[r];   // U1[0][r]
  }
  m0[wid][c] = m0v;
  __syncthreads();
  // alpha GEMM + smooth lrelu + head dot
  float av = ba[c];
  #pragma unroll 8
  for (int k=0;k<64;k++) av += m0[wid][k]*Wa[k*64+c];
  const float sl = 0.2f*av + 0.8f*av*sigmoidf_(av);
  float t = sl*adot[c];
  t += __shfl_xor(t,1,64);
  t += __shfl_xor(t,2,64);
  t += __shfl_xor(t,4,64);
  if ((c&7)==0){
    const int k = c>>3;
    alog[e*8+k] = t;
    unsigned u = __float_as_uint(t);
    u = (u & 0x80000000u) ? ~u : (u | 0x80000000u);
    atomicMax(&amaxu[dst*8+k], u);
  }
}

// K3: p = exp(a - amax[dst]); asum[dst] += p
__global__ __launch_bounds__(256) void k_softmax(
    const float* __restrict__ alog, const unsigned int* __restrict__ amaxu,
    const int* __restrict__ edst, float* __restrict__ p, float* __restrict__ asum)
{
  const int i = blockIdx.x*256 + threadIdx.x;   // EE*HH exact multiple of 256
  const int e = i>>3, k = i&7;
  const int dst = edst[e];
  unsigned u = amaxu[dst*8+k];
  unsigned ub = (u & 0x80000000u) ? (u & 0x7fffffffu) : ~u;
  const float mx = __uint_as_float(ub);
  const float pv = __expf(alog[i]-mx);
  p[i] = pv;
  atomicAdd(&asum[dst*8+k], pv);
}

// K4: recompute radial+msg2, value GEMM + gating + cp_tp2, weighted scatter-add
__global__ __launch_bounds__(256) void k_edge_b(
    const float* __restrict__ xsrc, const float* __restrict__ xdst,
    const float* __restrict__ eattr, const float* __restrict__ escal,
    const float* __restrict__ w1, const float* __restrict__ b1,
    const float* __restrict__ lnw, const float* __restrict__ lnb,
    const float* __restrict__ w2, const float* __restrict__ woff,
    const float* __restrict__ U1, const float* __restrict__ V1, const float* __restrict__ Y1,
    const float* __restrict__ U2, const float* __restrict__ V2, const float* __restrict__ Y2,
    const float* __restrict__ Wv, const float* __restrict__ bv,
    const int* __restrict__ esrc, const int* __restrict__ edst,
    const float* __restrict__ p, const float* __restrict__ asum,
    float* __restrict__ accum)
{
  const int wid = threadIdx.x >> 6;
  const int c   = threadIdx.x & 63;
  const int e   = blockIdx.x*4 + wid;
  __shared__ float sbuf[4][64];
  __shared__ float sh9[4][9];
  __shared__ float sU1[81], sV1[81], sY1[81];
  __shared__ float sU2[81], sV2[81], sY2[81];
  __shared__ float ms[4][9][64];
  __shared__ float cf[4][8];
  const int src = esrc[e], dst = edst[e];
  sbuf[wid][c] = escal[e*64+c];
  if (c<9) sh9[wid][c] = eattr[e*9+c];
  for (int i=threadIdx.x; i<81; i+=256){
    sU1[i]=U1[i]; sV1[i]=V1[i]; sY1[i]=Y1[i];
    sU2[i]=U2[i]; sV2[i]=V2[i]; sY2[i]=Y2[i];
  }
  if (c<8) cf[wid][c] = p[e*8+c] / (asum[dst*8+c] + 1e-16f);
  __syncthreads();
  // radial layer 1 + LN + silu
  float hh = b1[c];
  #pragma unroll 8
  for (int k=0;k<64;k++) hh += sbuf[wid][k]*w1[k*64+c];
  float s = hh;
  #pragma unroll
  for (int m=1;m<64;m<<=1) s += __shfl_xor(s,m,64);
  const float mean = s*(1.0f/64.0f);
  const float dv = hh-mean;
  float q = dv*dv;
  #pragma unroll
  for (int m=1;m<64;m<<=1) q += __shfl_xor(q,m,64);
  const float inv = rsqrtf(q*(1.0f/64.0f)+1e-5f);
  const float g = dv*inv*lnw[c]+lnb[c];
  const float h2 = g*sigmoidf_(g);
  __syncthreads();
  sbuf[wid][c] = h2;
  __syncthreads();
  // gather
  float msg[9];
  { const float* ps = xsrc + (size_t)src*576 + c;
    const float* pd = xdst + (size_t)dst*576 + c;
    #pragma unroll
    for (int l=0;l<9;l++) msg[l] = ps[l*64] + pd[l*64]; }
  // radial w[r] and cp_tp1 combine
  float wv[9], tmp1[9];
  #pragma unroll
  for (int r=0;r<9;r++){
    float t = woff[r*64+c];
    #pragma unroll 8
    for (int k=0;k<64;k++) t += sbuf[wid][k]*w2[k*576+r*64+c];
    wv[r] = t;
    float yv=0.f, xvv=0.f;
    #pragma unroll
    for (int l=0;l<9;l++){ yv += sh9[wid][l]*sY1[l*9+r]; xvv += msg[l]*sV1[l*9+r]; }
    tmp1[r] = xvv*yv*t;
  }
  // msg2 -> LDS
  #pragma unroll
  for (int l=0;l<9;l++){
    float m2 = 0.f;
    #pragma unroll
    for (int r=0;r<9;r++) m2 += tmp1[r]*sU1[l*9+r];
    ms[wid][l][c] = m2;
  }
  __syncthreads();
  // gate from l=0 row, cols 64..127
  float ga = bv[64+c];
  #pragma unroll 8
  for (int k=0;k<64;k++) ga += ms[wid][0][k]*Wv[k*128+64+c];
  const float gate = sigmoidf_(ga);
  // val rows
  float vvv[9];
  #pragma unroll
  for (int l=0;l<9;l++){
    float a = (l==0)? bv[c] : 0.0f;
    #pragma unroll 8
    for (int k=0;k<64;k++) a += ms[wid][l][k]*Wv[k*128+c];
    vvv[l]=a;
  }
  vvv[0] = vvv[0]*sigmoidf_(vvv[0]);
  #pragma unroll
  for (int l=1;l<9;l++) vvv[l] *= gate;
  // cp_tp2
  float tmp2[9];
  #pragma unroll
  for (int r=0;r<9;r++){
    float yv=0.f, xvv=0.f;
    #pragma unroll
    for (int l=0;l<9;l++){ yv += sh9[wid][l]*sY2[l*9+r]; xvv += vvv[l]*sV2[l*9+r]; }
    tmp2[r] = xvv*yv*wv[r];
  }
  const float myc = cf[wid][c>>3];
  float* ap = accum + (size_t)dst*576 + c;
  #pragma unroll
  for (int l=0;l<9;l++){
    float o = 0.f;
    #pragma unroll
    for (int r=0;r<9;r++) o += tmp2[r]*sU2[l*9+r];
    atomicAdd(ap + l*64, o*myc);
  }
}

// K5: out = accum @ W_proj (+b_proj on l==0)
__global__ __launch_bounds__(256) void k_proj(
    const float* __restrict__ acc, const float* __restrict__ Wp, const float* __restrict__ bp,
    float* __restrict__ out)
{
  const int wid = threadIdx.x>>6;
  const int c   = threadIdx.x&63;
  const int row = blockIdx.x*4 + wid;
  __shared__ float xr[4][64];
  xr[wid][c] = acc[row*64+c];
  __syncthreads();
  float o = (row % LL == 0) ? bp[c] : 0.f;
  #pragma unroll 8
  for (int k=0;k<64;k++) o += xr[wid][k]*Wp[k*64+c];
  out[row*64+c] = o;
}

extern "C" void kernel_launch(void* const* d_in, const int* in_sizes, int n_in,
                              void* d_out, int out_size, void* d_ws, size_t ws_size,
                              hipStream_t stream)
{
  const float* node_input = (const float*)d_in[0];
  const float* edge_attr  = (const float*)d_in[1];
  const float* edge_scal  = (const float*)d_in[2];
  const float* W_src   = (const float*)d_in[3];
  const float* b_src   = (const float*)d_in[4];
  const float* W_dst   = (const float*)d_in[5];
  const float* rad_w1  = (const float*)d_in[6];
  const float* rad_b1  = (const float*)d_in[7];
  const float* rad_ln_w= (const float*)d_in[8];
  const float* rad_ln_b= (const float*)d_in[9];
  const float* rad_w2  = (const float*)d_in[10];
  const float* rad_off = (const float*)d_in[11];
  const float* U1 = (const float*)d_in[12];
  const float* V1 = (const float*)d_in[13];
  const float* Y1 = (const float*)d_in[14];
  const float* U2 = (const float*)d_in[15];
  const float* V2 = (const float*)d_in[16];
  const float* Y2 = (const float*)d_in[17];
  const float* W_alpha = (const float*)d_in[18];
  const float* b_alpha = (const float*)d_in[19];
  const float* alpha_dot = (const float*)d_in[20];
  const float* W_value = (const float*)d_in[21];
  const float* b_value = (const float*)d_in[22];
  const float* W_proj  = (const float*)d_in[23];
  const float* b_proj  = (const float*)d_in[24];
  const int* esrc = (const int*)d_in[25];
  const int* edst = (const int*)d_in[26];

  float* xsrc  = (float*)d_ws;
  float* xdst  = xsrc + NLC;
  float* accum = xdst + NLC;
  float* alog  = accum + NLC;
  float* pbuf  = alog + (size_t)EE*HH;
  float* asum  = pbuf + (size_t)EE*HH;
  unsigned int* amaxu = (unsigned int*)(asum + (size_t)NN*HH);
  const size_t need = ((size_t)3*NLC + 2ull*EE*HH + 2ull*NN*HH)*sizeof(float);
  if (ws_size < need) return;   // workspace too small: bail (output stays invalid, visible in bench)

  hipMemsetAsync(accum, 0, (size_t)NLC*sizeof(float), stream);
  hipMemsetAsync(asum, 0, (size_t)NN*HH*sizeof(float), stream);
  hipMemsetAsync(amaxu, 0, (size_t)NN*HH*sizeof(unsigned int), stream);

  k_node_lin<<<NN*LL/4, 256, 0, stream>>>(node_input, W_src, b_src, W_dst, xsrc, xdst);
  k_edge_a<<<EE/4, 256, 0, stream>>>(xsrc, xdst, edge_attr, edge_scal,
      rad_w1, rad_b1, rad_ln_w, rad_ln_b, rad_w2, rad_off,
      U1, V1, Y1, W_alpha, b_alpha, alpha_dot, esrc, edst, alog, amaxu);
  k_softmax<<<(EE*HH)/256, 256, 0, stream>>>(alog, amaxu, edst, pbuf, asum);
  k_edge_b<<<EE/4, 256, 0, stream>>>(xsrc, xdst, edge_attr, edge_scal,
      rad_w1, rad_b1, rad_ln_w, rad_ln_b, rad_w2, rad_off,
      U1, V1, Y1, U2, V2, Y2, W_value, b_value, esrc, edst, pbuf, asum, accum);
  k_proj<<<NN*LL/4, 256, 0, stream>>>(accum, W_proj, b_proj, (float*)d_out);
}